// Round 1
// 1508.725 us; speedup vs baseline: 1.0720x; 1.0720x over previous
//
#include <hip/hip_runtime.h>
#include <hip/hip_bf16.h>
#include <math.h>

// Problem constants
#define NCLS 64
#define TDIM 128   // CDF_DIM
#define EMB  1024
#define NBATCH 16

// Tile config
#define BM 128
#define BN 128
#define BK 32

typedef __attribute__((ext_vector_type(8))) short bfrag8;   // 8 bf16 (4 VGPRs)
typedef __attribute__((ext_vector_type(4))) float ffrag4;   // 4 fp32 acc

// fp32 -> packed 2x bf16 (RNE)
__device__ __forceinline__ unsigned int pk2(float lo, float hi) {
    union { __hip_bfloat162 h; unsigned int u; } cv;
    cv.h = __float22bfloat162_rn(make_float2(lo, hi));
    return cv.u;
}
__device__ __forceinline__ short f2bs(float f) {
    return (short)(pk2(f, 0.f) & 0xffff);
}

union S8 { bfrag8 s; unsigned int u[4]; };

// async 16B global -> LDS (wave-uniform LDS base + lane*16 is the HW dest rule)
__device__ __forceinline__ void async16(const short* g, const short* l) {
    __builtin_amdgcn_global_load_lds(
        (const __attribute__((address_space(1))) unsigned int*)(unsigned long long)(uintptr_t)g,
        (__attribute__((address_space(3))) unsigned int*)(unsigned int)(uintptr_t)l,
        16, 0, 0);
}

// out[b*8192 + c*128 + t] = b2[c]
__global__ __launch_bounds__(256) void init_out(const float* __restrict__ b2,
                                                float* __restrict__ out) {
    int i = blockIdx.x * 256 + threadIdx.x;       // 0 .. 131071
    int c = (i >> 7) & (NCLS - 1);
    out[i] = b2[c];
}

// x fp32 [131072*1024] -> bf16 same layout. 8 elements/thread.
__global__ __launch_bounds__(256) void cvt_x(const float* __restrict__ x,
                                             short* __restrict__ xb) {
    size_t i = ((size_t)blockIdx.x * 256 + threadIdx.x) * 8;
    float4 a = *(const float4*)(x + i);
    float4 b = *(const float4*)(x + i + 4);
    S8 p;
    p.u[0] = pk2(a.x, a.y); p.u[1] = pk2(a.z, a.w);
    p.u[2] = pk2(b.x, b.y); p.u[3] = pk2(b.z, b.w);
    *(bfrag8*)(xb + i) = p.s;
}

// W1 fp32 [c][k][n] -> W1T bf16 [c][n][k]. 64x64 tile per block via LDS.
__global__ __launch_bounds__(256) void cvt_w1t(const float* __restrict__ W1,
                                               short* __restrict__ w1t) {
    const int bid = blockIdx.x;
    const int nt = bid & 15, kt = (bid >> 4) & 15, c = bid >> 8;
    const int t = threadIdx.x;
    __shared__ short ldsT[64 * 72];   // [n][k], row stride 72 shorts (144B, 16B-aligned)

    const float* src = W1 + (size_t)c * 1048576 + (size_t)(kt * 64) * 1024 + nt * 64;
    const int kr = t >> 4, nq = (t & 15) * 4;
#pragma unroll
    for (int i = 0; i < 4; ++i) {
        int k = kr + i * 16;
        float4 v = *(const float4*)(src + (size_t)k * 1024 + nq);
        ldsT[(nq + 0) * 72 + k] = f2bs(v.x);
        ldsT[(nq + 1) * 72 + k] = f2bs(v.y);
        ldsT[(nq + 2) * 72 + k] = f2bs(v.z);
        ldsT[(nq + 3) * 72 + k] = f2bs(v.w);
    }
    __syncthreads();
    short* dst = w1t + (size_t)c * 1048576 + (size_t)(nt * 64) * 1024 + kt * 64;
#pragma unroll
    for (int p = 0; p < 2; ++p) {
        int chunk = t + p * 256;         // 512 chunks of 8 shorts
        int n = chunk >> 3, kc = chunk & 7;
        bfrag8 v = *(const bfrag8*)(ldsT + n * 72 + kc * 8);
        *(bfrag8*)(dst + (size_t)n * 1024 + kc * 8) = v;
    }
}

// ---------------- fast path: 2-phase double-buffered bf16 GEMM + fused epilogue --------
// grid: 64 classes * 16 m-blocks * 8 n-blocks, 256 threads (4 waves).
// Block swizzle: all 128 blocks of a class land on one XCD (8 classes/XCD) so the
// per-K-step A/B slices (~200 KB) stay L2-resident.
__global__ __launch_bounds__(256) void mlp_gemm(
    const short* __restrict__ xb, const short* __restrict__ w1t,
    const float* __restrict__ b1, const float* __restrict__ W2,
    float* __restrict__ out)
{
    const int bid = blockIdx.x;
    // bijective XCD swizzle: xcd = bid & 7, 1024 blocks per XCD = 8 classes * 128
    const int xcd = bid & 7;
    const int idx = bid >> 3;               // 0..1023
    const int c   = ((idx >> 7) << 3) | xcd; // class, c % 8 == xcd
    const int w   = idx & 127;
    const int mb  = w >> 3;                  // batch index 0..15
    const int nb  = w & 7;                   // n-block 0..7

    // frag-major LDS: [tile16 (8)][quad (4)][l16 (16)][8 bf16]; tile = 512 shorts
    // double-buffered: 2 x 8KB per operand = 32KB total
    __shared__ __align__(16) short lds_a[2 * BM * BK];
    __shared__ __align__(16) short lds_b[2 * BN * BK];

    const int tid  = threadIdx.x;
    const int lane = tid & 63;
    const int wave = tid >> 6;        // 0..3
    const int wm = wave >> 1, wn = wave & 1;
    const int quad = lane >> 4, l16 = lane & 15;

    // ---- staging: wave w stages A-tiles {2w,2w+1} and B-tiles {2w,2w+1}.
    // lane l -> (tile, quad=l>>4, l16=l&15): global row tile*16+l16, k-chunk l>>4.
    const short* gA0 = xb + ((size_t)mb * 8192 + c * 128 + (2 * wave) * 16 + l16) * 1024
                          + quad * 8;
    const short* gA1 = gA0 + 16 * 1024;
    const short* gB0 = w1t + (size_t)c * 1048576
                           + (size_t)(nb * 128 + (2 * wave) * 16 + l16) * 1024 + quad * 8;
    const short* gB1 = gB0 + 16 * 1024;
    const int stA = (2 * wave) * 512;        // wave-uniform LDS tile base (shorts)

    ffrag4 acc[4][4] = {};

    // ---- prologue: stage k-tile 0 into buffer 0 ----
    async16(gA0, lds_a + stA);
    async16(gA1, lds_a + stA + 512);
    async16(gB0, lds_b + stA);
    async16(gB1, lds_b + stA + 512);
    gA0 += BK; gA1 += BK; gB0 += BK; gB1 += BK;
    __syncthreads();   // drains vmcnt(0): tile 0 visible

    int cur = 0;
    for (int kt = 0; kt < EMB / BK; ++kt) {
        const short* la = lds_a + cur * (BM * BK);
        const short* lb = lds_b + cur * (BN * BK);

        // issue next tile's loads FIRST -> latency hides under ds_read + MFMA
        if (kt + 1 < EMB / BK) {
            short* na = (short*)(lds_a + (cur ^ 1) * (BM * BK) + stA);
            short* nbp = (short*)(lds_b + (cur ^ 1) * (BN * BK) + stA);
            async16(gA0, na);
            async16(gA1, na + 512);
            async16(gB0, nbp);
            async16(gB1, nbp + 512);
            gA0 += BK; gA1 += BK; gB0 += BK; gB1 += BK;
        }

        const short* ard = la + (wm * 4) * 512 + quad * 128 + l16 * 8;
        const short* brd = lb + (wn * 4) * 512 + quad * 128 + l16 * 8;
        bfrag8 af[4], bf[4];
#pragma unroll
        for (int mi = 0; mi < 4; ++mi) af[mi] = *(const bfrag8*)(ard + mi * 512);
#pragma unroll
        for (int ni = 0; ni < 4; ++ni) bf[ni] = *(const bfrag8*)(brd + ni * 512);
#pragma unroll
        for (int mi = 0; mi < 4; ++mi)
#pragma unroll
            for (int ni = 0; ni < 4; ++ni)
                acc[mi][ni] = __builtin_amdgcn_mfma_f32_16x16x32_bf16(
                    af[mi], bf[ni], acc[mi][ni], 0, 0, 0);

        __syncthreads();   // prefetch complete + all reads of buf[cur] done
        cur ^= 1;
    }

    // ---- epilogue: out[m] += sum_n gelu(h + b1[n]) * W2[n] ----
    const int nbase = c * 1024 + nb * 128 + wn * 64 + l16;
    float b1v[4], w2v[4];
#pragma unroll
    for (int ni = 0; ni < 4; ++ni) {
        b1v[ni] = b1[nbase + ni * 16];
        w2v[ni] = W2[nbase + ni * 16];
    }

    float* outp = out + (size_t)mb * 8192 + c * 128 + wm * 64 + quad * 4;
#pragma unroll
    for (int mi = 0; mi < 4; ++mi) {
        float s[4] = {0.f, 0.f, 0.f, 0.f};
#pragma unroll
        for (int ni = 0; ni < 4; ++ni) {
#pragma unroll
            for (int r = 0; r < 4; ++r) {
                float h = acc[mi][ni][r] + b1v[ni];
                float g = 0.5f * h * (1.0f + erff(h * 0.70710678118654752f));
                s[r] += g * w2v[ni];
            }
        }
#pragma unroll
        for (int r = 0; r < 4; ++r) {
            s[r] += __shfl_xor(s[r], 8, 64);
            s[r] += __shfl_xor(s[r], 4, 64);
            s[r] += __shfl_xor(s[r], 2, 64);
            s[r] += __shfl_xor(s[r], 1, 64);
            if (l16 == 0) atomicAdd(outp + mi * 16 + r, s[r]);
        }
    }
}

// ---------------- fallback (round-0 kernel, used if ws too small) ----------------
__global__ __launch_bounds__(256) void mlp_head_fallback(
    const float* __restrict__ x,  const float* __restrict__ W1,
    const float* __restrict__ b1, const float* __restrict__ W2,
    float* __restrict__ out)
{
    const int bid = blockIdx.x;
    const int nb = bid & 7;
    const int mb = (bid >> 3) & 15;
    const int c  = bid >> 7;

    __shared__ __align__(16) short lds_a[BM * BK];
    __shared__ __align__(16) short lds_b[BN * BK];

    const int tid  = threadIdx.x;
    const int lane = tid & 63;
    const int wave = tid >> 6;
    const int wm = wave >> 1, wn = wave & 1;
    const int quad = lane >> 4, l16 = lane & 15;

    const int arow = tid & 127;
    const int akh  = tid >> 7;
    const float* aptr = x + ((size_t)mb * 8192 + (size_t)c * 128 + arow) * 1024 + akh * 16;
    short* aw0 = lds_a + (arow >> 4) * 512 + (akh * 2) * 128 + (arow & 15) * 8;
    short* aw1 = aw0 + 128;

    const int ncol = tid & 127;
    const int bkh  = tid >> 7;
    const float* bptr = W1 + (size_t)c * 1024 * 1024 + (size_t)(bkh * 16) * 1024
                           + (size_t)nb * 128 + ncol;
    short* bw0 = lds_b + (ncol >> 4) * 512 + (bkh * 2) * 128 + (ncol & 15) * 8;
    short* bw1 = bw0 + 128;

    const short* ard = lds_a + (wm * 4) * 512 + quad * 128 + l16 * 8;
    const short* brd = lds_b + (wn * 4) * 512 + quad * 128 + l16 * 8;

    ffrag4 acc[4][4] = {};

    for (int kt = 0; kt < EMB / BK; ++kt) {
        float4 a0 = *(const float4*)(aptr + 0);
        float4 a1 = *(const float4*)(aptr + 4);
        float4 a2 = *(const float4*)(aptr + 8);
        float4 a3 = *(const float4*)(aptr + 12);
        float bv[16];
#pragma unroll
        for (int j = 0; j < 16; ++j) bv[j] = bptr[(size_t)j * 1024];
        aptr += BK;
        bptr += (size_t)BK * 1024;

        __syncthreads();

        S8 pa0, pa1, pb0, pb1;
        pa0.u[0] = pk2(a0.x, a0.y); pa0.u[1] = pk2(a0.z, a0.w);
        pa0.u[2] = pk2(a1.x, a1.y); pa0.u[3] = pk2(a1.z, a1.w);
        pa1.u[0] = pk2(a2.x, a2.y); pa1.u[1] = pk2(a2.z, a2.w);
        pa1.u[2] = pk2(a3.x, a3.y); pa1.u[3] = pk2(a3.z, a3.w);
#pragma unroll
        for (int j = 0; j < 4; ++j) pb0.u[j] = pk2(bv[2 * j], bv[2 * j + 1]);
#pragma unroll
        for (int j = 0; j < 4; ++j) pb1.u[j] = pk2(bv[8 + 2 * j], bv[9 + 2 * j]);

        *(bfrag8*)aw0 = pa0.s;
        *(bfrag8*)aw1 = pa1.s;
        *(bfrag8*)bw0 = pb0.s;
        *(bfrag8*)bw1 = pb1.s;

        __syncthreads();

        bfrag8 af[4], bf[4];
#pragma unroll
        for (int mi = 0; mi < 4; ++mi) af[mi] = *(const bfrag8*)(ard + mi * 512);
#pragma unroll
        for (int ni = 0; ni < 4; ++ni) bf[ni] = *(const bfrag8*)(brd + ni * 512);
#pragma unroll
        for (int mi = 0; mi < 4; ++mi)
#pragma unroll
            for (int ni = 0; ni < 4; ++ni)
                acc[mi][ni] = __builtin_amdgcn_mfma_f32_16x16x32_bf16(
                    af[mi], bf[ni], acc[mi][ni], 0, 0, 0);
    }

    const int nbase = c * 1024 + nb * 128 + wn * 64 + l16;
    float b1v[4], w2v[4];
#pragma unroll
    for (int ni = 0; ni < 4; ++ni) {
        b1v[ni] = b1[nbase + ni * 16];
        w2v[ni] = W2[nbase + ni * 16];
    }

    float* outp = out + (size_t)mb * 8192 + c * 128 + wm * 64 + quad * 4;
#pragma unroll
    for (int mi = 0; mi < 4; ++mi) {
        float s[4] = {0.f, 0.f, 0.f, 0.f};
#pragma unroll
        for (int ni = 0; ni < 4; ++ni) {
#pragma unroll
            for (int r = 0; r < 4; ++r) {
                float h = acc[mi][ni][r] + b1v[ni];
                float g = 0.5f * h * (1.0f + erff(h * 0.70710678118654752f));
                s[r] += g * w2v[ni];
            }
        }
#pragma unroll
        for (int r = 0; r < 4; ++r) {
            s[r] += __shfl_xor(s[r], 8, 64);
            s[r] += __shfl_xor(s[r], 4, 64);
            s[r] += __shfl_xor(s[r], 2, 64);
            s[r] += __shfl_xor(s[r], 1, 64);
            if (l16 == 0) atomicAdd(outp + mi * 16 + r, s[r]);
        }
    }
}

extern "C" void kernel_launch(void* const* d_in, const int* in_sizes, int n_in,
                              void* d_out, int out_size, void* d_ws, size_t ws_size,
                              hipStream_t stream) {
    const float* x  = (const float*)d_in[0];
    const float* W1 = (const float*)d_in[1];
    const float* b1 = (const float*)d_in[2];
    const float* W2 = (const float*)d_in[3];
    const float* b2 = (const float*)d_in[4];
    float* out = (float*)d_out;

    const size_t xb_bytes  = (size_t)NBATCH * NCLS * TDIM * EMB * 2;      // 268435456
    const size_t w1t_bytes = (size_t)NCLS * EMB * EMB * 2;                // 134217728

    init_out<<<dim3(512), dim3(256), 0, stream>>>(b2, out);

    if (ws_size >= xb_bytes + w1t_bytes) {
        short* xb  = (short*)d_ws;
        short* w1t = (short*)((char*)d_ws + xb_bytes);
        cvt_x<<<dim3(65536), dim3(256), 0, stream>>>(x, xb);
        cvt_w1t<<<dim3(16384), dim3(256), 0, stream>>>(W1, w1t);
        mlp_gemm<<<dim3(NCLS * 16 * 8), dim3(256), 0, stream>>>(xb, w1t, b1, W2, out);
    } else {
        mlp_head_fallback<<<dim3(NCLS * 16 * 8), dim3(256), 0, stream>>>(x, W1, b1, W2, out);
    }
}

// Round 2
// 1396.191 us; speedup vs baseline: 1.1584x; 1.0806x over previous
//
#include <hip/hip_runtime.h>
#include <hip/hip_bf16.h>
#include <math.h>

// Problem constants
#define NCLS 64
#define TDIM 128   // CDF_DIM
#define EMB  1024
#define NBATCH 16

// Tile config
#define BM 128
#define BN 128
#define BK 32
#define NT (EMB / BK)          // 32 K-tiles
#define BUFSH 8192             // shorts per circular buffer (A 4096 + B 4096)

typedef __attribute__((ext_vector_type(8))) short bfrag8;   // 8 bf16 (4 VGPRs)
typedef __attribute__((ext_vector_type(4))) float ffrag4;   // 4 fp32 acc

// fp32 -> packed 2x bf16 (RNE)
__device__ __forceinline__ unsigned int pk2(float lo, float hi) {
    union { __hip_bfloat162 h; unsigned int u; } cv;
    cv.h = __float22bfloat162_rn(make_float2(lo, hi));
    return cv.u;
}
__device__ __forceinline__ short f2bs(float f) {
    return (short)(pk2(f, 0.f) & 0xffff);
}

union S8 { bfrag8 s; unsigned int u[4]; };

// async 16B global -> LDS (wave-uniform LDS base + lane*16 is the HW dest rule)
__device__ __forceinline__ void async16(const short* g, const short* l) {
    __builtin_amdgcn_global_load_lds(
        (const __attribute__((address_space(1))) unsigned int*)(unsigned long long)(uintptr_t)g,
        (__attribute__((address_space(3))) unsigned int*)(unsigned int)(uintptr_t)l,
        16, 0, 0);
}

// Exact-GELU via Abramowitz-Stegun 7.1.26 erf (|err| <= 1.5e-7):
// gelu(h) = 0.5h + 0.5|h| * erf(|h|/sqrt2)   (sign folded into the |h| term)
__device__ __forceinline__ float gelu_fast(float h) {
    float az = fabsf(h) * 0.70710678118654752f;
    float t  = __builtin_amdgcn_rcpf(fmaf(0.3275911f, az, 1.0f));
    float p  = fmaf(1.061405429f, t, -1.453152027f);
    p = fmaf(p, t, 1.421413741f);
    p = fmaf(p, t, -0.284496736f);
    p = fmaf(p, t, 0.254829592f);
    p = p * t;
    float e = __expf(-az * az);
    float y = fmaf(-p, e, 1.0f);           // erf(|h|/sqrt2)
    return fmaf(0.5f * fabsf(h), y, 0.5f * h);
}

// out[b*8192 + c*128 + t] = b2[c]
__global__ __launch_bounds__(256) void init_out(const float* __restrict__ b2,
                                                float* __restrict__ out) {
    int i = blockIdx.x * 256 + threadIdx.x;       // 0 .. 131071
    int c = (i >> 7) & (NCLS - 1);
    out[i] = b2[c];
}

// x fp32 [131072*1024] -> bf16 same layout. 8 elements/thread.
__global__ __launch_bounds__(256) void cvt_x(const float* __restrict__ x,
                                             short* __restrict__ xb) {
    size_t i = ((size_t)blockIdx.x * 256 + threadIdx.x) * 8;
    float4 a = *(const float4*)(x + i);
    float4 b = *(const float4*)(x + i + 4);
    S8 p;
    p.u[0] = pk2(a.x, a.y); p.u[1] = pk2(a.z, a.w);
    p.u[2] = pk2(b.x, b.y); p.u[3] = pk2(b.z, b.w);
    *(bfrag8*)(xb + i) = p.s;
}

// W1 fp32 [c][k][n] -> W1T bf16 [c][n][k]. 64x64 tile per block via LDS.
__global__ __launch_bounds__(256) void cvt_w1t(const float* __restrict__ W1,
                                               short* __restrict__ w1t) {
    const int bid = blockIdx.x;
    const int nt = bid & 15, kt = (bid >> 4) & 15, c = bid >> 8;
    const int t = threadIdx.x;
    __shared__ short ldsT[64 * 72];   // [n][k], row stride 72 shorts (144B, 16B-aligned)

    const float* src = W1 + (size_t)c * 1048576 + (size_t)(kt * 64) * 1024 + nt * 64;
    const int kr = t >> 4, nq = (t & 15) * 4;
#pragma unroll
    for (int i = 0; i < 4; ++i) {
        int k = kr + i * 16;
        float4 v = *(const float4*)(src + (size_t)k * 1024 + nq);
        ldsT[(nq + 0) * 72 + k] = f2bs(v.x);
        ldsT[(nq + 1) * 72 + k] = f2bs(v.y);
        ldsT[(nq + 2) * 72 + k] = f2bs(v.z);
        ldsT[(nq + 3) * 72 + k] = f2bs(v.w);
    }
    __syncthreads();
    short* dst = w1t + (size_t)c * 1048576 + (size_t)(nt * 64) * 1024 + kt * 64;
#pragma unroll
    for (int p = 0; p < 2; ++p) {
        int chunk = t + p * 256;         // 512 chunks of 8 shorts
        int n = chunk >> 3, kc = chunk & 7;
        bfrag8 v = *(const bfrag8*)(ldsT + n * 72 + kc * 8);
        *(bfrag8*)(dst + (size_t)n * 1024 + kc * 8) = v;
    }
}

// ---------------- fast path: 3-deep pipelined bf16 GEMM, counted vmcnt --------
// grid: 64 classes * 16 m-blocks * 8 n-blocks, 256 threads (4 waves).
// Schedule per K-tile t: issue stage(t+2) -> ds_read buf[t%3] -> lgkmcnt(0) ->
// 16 MFMA (setprio 1) -> vmcnt(4) [tile t+1 landed, 4 newest may fly] -> s_barrier.
// One barrier per tile; vmcnt never drained to 0 in steady state (T3/T4).
__global__ __launch_bounds__(256, 3) void mlp_gemm(
    const short* __restrict__ xb, const short* __restrict__ w1t,
    const float* __restrict__ b1, const float* __restrict__ W2,
    float* __restrict__ out)
{
    const int bid = blockIdx.x;
    // bijective XCD swizzle: xcd = bid & 7, 1024 blocks per XCD = 8 classes * 128
    const int xcd = bid & 7;
    const int idx = bid >> 3;               // 0..1023
    const int c   = ((idx >> 7) << 3) | xcd; // class, c % 8 == xcd
    const int w   = idx & 127;
    const int mb  = w >> 3;                  // batch index 0..15
    const int nb  = w & 7;                   // n-block 0..7

    // 3 circular buffers; each: A frag-major 4096 shorts, then B 4096 shorts.
    __shared__ __align__(16) short lds[3 * BUFSH];   // 48 KB -> 3 blocks/CU

    const int tid  = threadIdx.x;
    const int lane = tid & 63;
    const int wave = tid >> 6;        // 0..3
    const int wm = wave >> 1, wn = wave & 1;
    const int quad = lane >> 4, l16 = lane & 15;

    // staging: wave w stages A-subtiles {2w,2w+1} and B-subtiles {2w,2w+1}.
    const short* gA0 = xb + ((size_t)mb * 8192 + c * 128 + (2 * wave) * 16 + l16) * 1024
                          + quad * 8;
    const short* gA1 = gA0 + 16 * 1024;
    const short* gB0 = w1t + (size_t)c * 1048576
                           + (size_t)(nb * 128 + (2 * wave) * 16 + l16) * 1024 + quad * 8;
    const short* gB1 = gB0 + 16 * 1024;
    const int stA = (2 * wave) * 512;          // wave-uniform, within A region
    const int stB = 4096 + (2 * wave) * 512;   // wave-uniform, within B region

    // fragment read offsets (within a buffer)
    const int ardo = (wm * 4) * 512 + quad * 128 + l16 * 8;
    const int brdo = 4096 + (wn * 4) * 512 + quad * 128 + l16 * 8;

    ffrag4 acc[4][4] = {};

    // ---- prologue: stage tiles 0 -> buf0, 1 -> buf1 ----
    async16(gA0, lds + stA);        async16(gA1, lds + stA + 512);
    async16(gB0, lds + stB);        async16(gB1, lds + stB + 512);
    gA0 += BK; gA1 += BK; gB0 += BK; gB1 += BK;
    async16(gA0, lds + BUFSH + stA); async16(gA1, lds + BUFSH + stA + 512);
    async16(gB0, lds + BUFSH + stB); async16(gB1, lds + BUFSH + stB + 512);
    gA0 += BK; gA1 += BK; gB0 += BK; gB1 += BK;
    asm volatile("s_waitcnt vmcnt(4)" ::: "memory");   // tile 0 landed
    __builtin_amdgcn_sched_barrier(0);
    __builtin_amdgcn_s_barrier();
    __builtin_amdgcn_sched_barrier(0);

    int qr = 0;   // buffer being read (tile t)
    int qs = 2;   // buffer being staged (tile t+2)
    for (int t = 0; t < NT; ++t) {
        if (t < NT - 2) {
            const short* sb = lds + qs * BUFSH;
            async16(gA0, sb + stA); async16(gA1, sb + stA + 512);
            async16(gB0, sb + stB); async16(gB1, sb + stB + 512);
            gA0 += BK; gA1 += BK; gB0 += BK; gB1 += BK;
        }
        const short* rb = lds + qr * BUFSH;
        bfrag8 af[4], bf[4];
#pragma unroll
        for (int mi = 0; mi < 4; ++mi) af[mi] = *(const bfrag8*)(rb + ardo + mi * 512);
#pragma unroll
        for (int ni = 0; ni < 4; ++ni) bf[ni] = *(const bfrag8*)(rb + brdo + ni * 512);
        asm volatile("s_waitcnt lgkmcnt(0)" ::: "memory");
        __builtin_amdgcn_sched_barrier(0);        // rule #18: MFMA must not hoist
        __builtin_amdgcn_s_setprio(1);
#pragma unroll
        for (int mi = 0; mi < 4; ++mi)
#pragma unroll
            for (int ni = 0; ni < 4; ++ni)
                acc[mi][ni] = __builtin_amdgcn_mfma_f32_16x16x32_bf16(
                    af[mi], bf[ni], acc[mi][ni], 0, 0, 0);
        __builtin_amdgcn_s_setprio(0);
        __builtin_amdgcn_sched_barrier(0);
        if (t < NT - 2) {
            asm volatile("s_waitcnt vmcnt(4)" ::: "memory");   // tile t+1 landed
        } else if (t == NT - 2) {
            asm volatile("s_waitcnt vmcnt(0)" ::: "memory");   // last tile landed
        }
        if (t < NT - 1) {
            __builtin_amdgcn_sched_barrier(0);
            __builtin_amdgcn_s_barrier();    // publishes tile t+1; WAR fence for qs
            __builtin_amdgcn_sched_barrier(0);
        }
        qr = (qr == 2) ? 0 : qr + 1;
        qs = (qs == 2) ? 0 : qs + 1;
    }

    // ---- epilogue: out[m] += sum_n gelu(h + b1[n]) * W2[n] ----
    const int nbase = c * 1024 + nb * 128 + wn * 64 + l16;
    float b1v[4], w2v[4];
#pragma unroll
    for (int ni = 0; ni < 4; ++ni) {
        b1v[ni] = b1[nbase + ni * 16];
        w2v[ni] = W2[nbase + ni * 16];
    }

    float* outp = out + (size_t)mb * 8192 + c * 128 + wm * 64 + quad * 4;
#pragma unroll
    for (int mi = 0; mi < 4; ++mi) {
        float s[4] = {0.f, 0.f, 0.f, 0.f};
#pragma unroll
        for (int ni = 0; ni < 4; ++ni) {
#pragma unroll
            for (int r = 0; r < 4; ++r) {
                float h = acc[mi][ni][r] + b1v[ni];
                s[r] += gelu_fast(h) * w2v[ni];
            }
        }
#pragma unroll
        for (int r = 0; r < 4; ++r) {
            s[r] += __shfl_xor(s[r], 8, 64);
            s[r] += __shfl_xor(s[r], 4, 64);
            s[r] += __shfl_xor(s[r], 2, 64);
            s[r] += __shfl_xor(s[r], 1, 64);
            if (l16 == 0) atomicAdd(outp + mi * 16 + r, s[r]);
        }
    }
}

// ---------------- fallback (round-0 kernel, used if ws too small) ----------------
__global__ __launch_bounds__(256) void mlp_head_fallback(
    const float* __restrict__ x,  const float* __restrict__ W1,
    const float* __restrict__ b1, const float* __restrict__ W2,
    float* __restrict__ out)
{
    const int bid = blockIdx.x;
    const int nb = bid & 7;
    const int mb = (bid >> 3) & 15;
    const int c  = bid >> 7;

    __shared__ __align__(16) short lds_a[BM * BK];
    __shared__ __align__(16) short lds_b[BN * BK];

    const int tid  = threadIdx.x;
    const int lane = tid & 63;
    const int wave = tid >> 6;
    const int wm = wave >> 1, wn = wave & 1;
    const int quad = lane >> 4, l16 = lane & 15;

    const int arow = tid & 127;
    const int akh  = tid >> 7;
    const float* aptr = x + ((size_t)mb * 8192 + (size_t)c * 128 + arow) * 1024 + akh * 16;
    short* aw0 = lds_a + (arow >> 4) * 512 + (akh * 2) * 128 + (arow & 15) * 8;
    short* aw1 = aw0 + 128;

    const int ncol = tid & 127;
    const int bkh  = tid >> 7;
    const float* bptr = W1 + (size_t)c * 1024 * 1024 + (size_t)(bkh * 16) * 1024
                           + (size_t)nb * 128 + ncol;
    short* bw0 = lds_b + (ncol >> 4) * 512 + (bkh * 2) * 128 + (ncol & 15) * 8;
    short* bw1 = bw0 + 128;

    const short* ard = lds_a + (wm * 4) * 512 + quad * 128 + l16 * 8;
    const short* brd = lds_b + (wn * 4) * 512 + quad * 128 + l16 * 8;

    ffrag4 acc[4][4] = {};

    for (int kt = 0; kt < EMB / BK; ++kt) {
        float4 a0 = *(const float4*)(aptr + 0);
        float4 a1 = *(const float4*)(aptr + 4);
        float4 a2 = *(const float4*)(aptr + 8);
        float4 a3 = *(const float4*)(aptr + 12);
        float bv[16];
#pragma unroll
        for (int j = 0; j < 16; ++j) bv[j] = bptr[(size_t)j * 1024];
        aptr += BK;
        bptr += (size_t)BK * 1024;

        __syncthreads();

        S8 pa0, pa1, pb0, pb1;
        pa0.u[0] = pk2(a0.x, a0.y); pa0.u[1] = pk2(a0.z, a0.w);
        pa0.u[2] = pk2(a1.x, a1.y); pa0.u[3] = pk2(a1.z, a1.w);
        pa1.u[0] = pk2(a2.x, a2.y); pa1.u[1] = pk2(a2.z, a2.w);
        pa1.u[2] = pk2(a3.x, a3.y); pa1.u[3] = pk2(a3.z, a3.w);
#pragma unroll
        for (int j = 0; j < 4; ++j) pb0.u[j] = pk2(bv[2 * j], bv[2 * j + 1]);
#pragma unroll
        for (int j = 0; j < 4; ++j) pb1.u[j] = pk2(bv[8 + 2 * j], bv[9 + 2 * j]);

        *(bfrag8*)aw0 = pa0.s;
        *(bfrag8*)aw1 = pa1.s;
        *(bfrag8*)bw0 = pb0.s;
        *(bfrag8*)bw1 = pb1.s;

        __syncthreads();

        bfrag8 af[4], bf[4];
#pragma unroll
        for (int mi = 0; mi < 4; ++mi) af[mi] = *(const bfrag8*)(ard + mi * 512);
#pragma unroll
        for (int ni = 0; ni < 4; ++ni) bf[ni] = *(const bfrag8*)(brd + ni * 512);
#pragma unroll
        for (int mi = 0; mi < 4; ++mi)
#pragma unroll
            for (int ni = 0; ni < 4; ++ni)
                acc[mi][ni] = __builtin_amdgcn_mfma_f32_16x16x32_bf16(
                    af[mi], bf[ni], acc[mi][ni], 0, 0, 0);
    }

    const int nbase = c * 1024 + nb * 128 + wn * 64 + l16;
    float b1v[4], w2v[4];
#pragma unroll
    for (int ni = 0; ni < 4; ++ni) {
        b1v[ni] = b1[nbase + ni * 16];
        w2v[ni] = W2[nbase + ni * 16];
    }

    float* outp = out + (size_t)mb * 8192 + c * 128 + wm * 64 + quad * 4;
#pragma unroll
    for (int mi = 0; mi < 4; ++mi) {
        float s[4] = {0.f, 0.f, 0.f, 0.f};
#pragma unroll
        for (int ni = 0; ni < 4; ++ni) {
#pragma unroll
            for (int r = 0; r < 4; ++r) {
                float h = acc[mi][ni][r] + b1v[ni];
                s[r] += gelu_fast(h) * w2v[ni];
            }
        }
#pragma unroll
        for (int r = 0; r < 4; ++r) {
            s[r] += __shfl_xor(s[r], 8, 64);
            s[r] += __shfl_xor(s[r], 4, 64);
            s[r] += __shfl_xor(s[r], 2, 64);
            s[r] += __shfl_xor(s[r], 1, 64);
            if (l16 == 0) atomicAdd(outp + mi * 16 + r, s[r]);
        }
    }
}

extern "C" void kernel_launch(void* const* d_in, const int* in_sizes, int n_in,
                              void* d_out, int out_size, void* d_ws, size_t ws_size,
                              hipStream_t stream) {
    const float* x  = (const float*)d_in[0];
    const float* W1 = (const float*)d_in[1];
    const float* b1 = (const float*)d_in[2];
    const float* W2 = (const float*)d_in[3];
    const float* b2 = (const float*)d_in[4];
    float* out = (float*)d_out;

    const size_t xb_bytes  = (size_t)NBATCH * NCLS * TDIM * EMB * 2;      // 268435456
    const size_t w1t_bytes = (size_t)NCLS * EMB * EMB * 2;                // 134217728

    init_out<<<dim3(512), dim3(256), 0, stream>>>(b2, out);

    if (ws_size >= xb_bytes + w1t_bytes) {
        short* xb  = (short*)d_ws;
        short* w1t = (short*)((char*)d_ws + xb_bytes);
        cvt_x<<<dim3(65536), dim3(256), 0, stream>>>(x, xb);
        cvt_w1t<<<dim3(16384), dim3(256), 0, stream>>>(W1, w1t);
        mlp_gemm<<<dim3(NCLS * 16 * 8), dim3(256), 0, stream>>>(xb, w1t, b1, W2, out);
    } else {
        mlp_head_fallback<<<dim3(NCLS * 16 * 8), dim3(256), 0, stream>>>(x, W1, b1, W2, out);
    }
}

// Round 3
// 1348.918 us; speedup vs baseline: 1.1990x; 1.0350x over previous
//
#include <hip/hip_runtime.h>
#include <hip/hip_bf16.h>
#include <math.h>

// Problem constants
#define NCLS 64
#define TDIM 128   // CDF_DIM
#define EMB  1024
#define NBATCH 16

// ---- legacy 128^2 tile config (fallback kernel) ----
#define BM 128
#define BN 128
#define BK 32

// ---- 256^2 8-phase config (fast path) ----
#define BK2   64
#define KT2   (EMB / BK2)      // 16 K-tiles
#define ABUF  16384            // shorts: A region per buffer (256 rows x 64 k)
#define BUFSZ 32768            // shorts per buffer (A + B)

typedef __attribute__((ext_vector_type(8))) short bfrag8;   // 8 bf16 (4 VGPRs)
typedef __attribute__((ext_vector_type(4))) float ffrag4;   // 4 fp32 acc

// fp32 -> packed 2x bf16 (RNE)
__device__ __forceinline__ unsigned int pk2(float lo, float hi) {
    union { __hip_bfloat162 h; unsigned int u; } cv;
    cv.h = __float22bfloat162_rn(make_float2(lo, hi));
    return cv.u;
}
__device__ __forceinline__ short f2bs(float f) {
    return (short)(pk2(f, 0.f) & 0xffff);
}

union S8 { bfrag8 s; unsigned int u[4]; };

// async 16B global -> LDS (wave-uniform LDS base + lane*16 is the HW dest rule)
__device__ __forceinline__ void async16(const short* g, const short* l) {
    __builtin_amdgcn_global_load_lds(
        (const __attribute__((address_space(1))) unsigned int*)(unsigned long long)(uintptr_t)g,
        (__attribute__((address_space(3))) unsigned int*)(unsigned int)(uintptr_t)l,
        16, 0, 0);
}

// Exact-GELU via Abramowitz-Stegun 7.1.26 erf (|err| <= 1.5e-7)
__device__ __forceinline__ float gelu_fast(float h) {
    float az = fabsf(h) * 0.70710678118654752f;
    float t  = __builtin_amdgcn_rcpf(fmaf(0.3275911f, az, 1.0f));
    float p  = fmaf(1.061405429f, t, -1.453152027f);
    p = fmaf(p, t, 1.421413741f);
    p = fmaf(p, t, -0.284496736f);
    p = fmaf(p, t, 0.254829592f);
    p = p * t;
    float e = __expf(-az * az);
    float y = fmaf(-p, e, 1.0f);           // erf(|h|/sqrt2)
    return fmaf(0.5f * fabsf(h), y, 0.5f * h);
}

#define SBAR()  do { __builtin_amdgcn_sched_barrier(0); \
                     __builtin_amdgcn_s_barrier(); \
                     __builtin_amdgcn_sched_barrier(0); } while (0)
#define LGKM0() do { asm volatile("s_waitcnt lgkmcnt(0)" ::: "memory"); \
                     __builtin_amdgcn_sched_barrier(0); } while (0)

// out[b*8192 + c*128 + t] = b2[c]
__global__ __launch_bounds__(256) void init_out(const float* __restrict__ b2,
                                                float* __restrict__ out) {
    int i = blockIdx.x * 256 + threadIdx.x;       // 0 .. 131071
    int c = (i >> 7) & (NCLS - 1);
    out[i] = b2[c];
}

// x fp32 [131072*1024] -> bf16 same layout. 32 elements/thread.
__global__ __launch_bounds__(256) void cvt_x(const float* __restrict__ x,
                                             short* __restrict__ xb) {
    size_t i = ((size_t)blockIdx.x * 256 + threadIdx.x) * 32;
#pragma unroll
    for (int j = 0; j < 4; ++j) {
        float4 a = *(const float4*)(x + i + j * 8);
        float4 b = *(const float4*)(x + i + j * 8 + 4);
        S8 p;
        p.u[0] = pk2(a.x, a.y); p.u[1] = pk2(a.z, a.w);
        p.u[2] = pk2(b.x, b.y); p.u[3] = pk2(b.z, b.w);
        *(bfrag8*)(xb + i + j * 8) = p.s;
    }
}

// W1 fp32 [c][k][n] -> W1T bf16 [c][n][k]. 64x64 tile per block via LDS.
__global__ __launch_bounds__(256) void cvt_w1t(const float* __restrict__ W1,
                                               short* __restrict__ w1t) {
    const int bid = blockIdx.x;
    const int nt = bid & 15, kt = (bid >> 4) & 15, c = bid >> 8;
    const int t = threadIdx.x;
    __shared__ short ldsT[64 * 72];   // [n][k], row stride 72 shorts

    const float* src = W1 + (size_t)c * 1048576 + (size_t)(kt * 64) * 1024 + nt * 64;
    const int kr = t >> 4, nq = (t & 15) * 4;
#pragma unroll
    for (int i = 0; i < 4; ++i) {
        int k = kr + i * 16;
        float4 v = *(const float4*)(src + (size_t)k * 1024 + nq);
        ldsT[(nq + 0) * 72 + k] = f2bs(v.x);
        ldsT[(nq + 1) * 72 + k] = f2bs(v.y);
        ldsT[(nq + 2) * 72 + k] = f2bs(v.z);
        ldsT[(nq + 3) * 72 + k] = f2bs(v.w);
    }
    __syncthreads();
    short* dst = w1t + (size_t)c * 1048576 + (size_t)(nt * 64) * 1024 + kt * 64;
#pragma unroll
    for (int p = 0; p < 2; ++p) {
        int chunk = t + p * 256;         // 512 chunks of 8 shorts
        int n = chunk >> 3, kc = chunk & 7;
        bfrag8 v = *(const bfrag8*)(ldsT + n * 72 + kc * 8);
        *(bfrag8*)(dst + (size_t)n * 1024 + kc * 8) = v;
    }
}

// ---------------- fast path: 256^2 8-phase bf16 GEMM + fused GELU/W2 epilogue ----
// 512 threads = 8 waves (2M x 4N); per-wave output 128x64; BK=64; 2 LDS buffers.
// Per K-tile: 4 phases x 16 MFMA. Staging runs 1 tile + 2 half-tiles ahead:
// phases 2/3 of tile t stage B then A of tile t+2 into buf[t&1] (slots past their
// last read, fenced by phase-end barriers). Boundary wait = vmcnt(8), never 0.
__global__ __launch_bounds__(512, 2) void mlp_gemm8(
    const short* __restrict__ xb, const short* __restrict__ w1t,
    const float* __restrict__ b1, const float* __restrict__ W2,
    float* __restrict__ out)
{
    const int bid = blockIdx.x;
    // XCD swizzle: 8 classes per XCD; 256 blocks per XCD (2048 total, bijective)
    const int xcd = bid & 7;
    const int idx = bid >> 3;               // 0..255
    const int c   = ((idx >> 5) << 3) | xcd;
    const int w5  = idx & 31;
    const int mb  = w5 >> 2;                // m-block 0..7 (256 rows each)
    const int nb2 = w5 & 3;                 // n-block 0..3 (256 cols each)

    __shared__ __align__(16) short lds[2 * BUFSZ];   // 128 KB

    const int tid  = threadIdx.x;
    const int lane = tid & 63;
    const int wave = tid >> 6;              // 0..7
    const int wm = wave >> 2, wn = wave & 3;
    const int quad = lane >> 4, l16 = lane & 15;
    const int lo8  = lane * 8;              // lane frag offset (shorts)

    // staging pointers: wave stages m16/n16 = h*8+wave, kh in {0,1} (+kh*32)
    const short* gA0 = xb + ((size_t)(mb * 2 + 0) * 8192 + c * 128 + wave * 16 + l16) * 1024
                          + quad * 8;
    const short* gA1 = xb + ((size_t)(mb * 2 + 1) * 8192 + c * 128 + wave * 16 + l16) * 1024
                          + quad * 8;
    const short* gB0 = w1t + (size_t)c * 1048576
                           + (size_t)(nb2 * 256 + wave * 16 + l16) * 1024 + quad * 8;
    const short* gB1 = gB0 + (size_t)128 * 1024;   // n16 += 8
    // wave-uniform LDS dest offsets: frag (t16, kh) at (t16*2+kh)*512 (+ABUF for B)
    const int dA0 = (wave * 2) * 512;               // h=0: m16 = wave
    const int dA1 = ((8 + wave) * 2) * 512;         // h=1: m16 = 8+wave
    const int dB0 = ABUF + (wave * 2) * 512;
    const int dB1 = ABUF + ((8 + wave) * 2) * 512;

    ffrag4 acc[8][4] = {};
    bfrag8 af[4][2], bf[4][2];

    // ---- prologue: stage tile0 -> buf0, tile1 -> buf1 (8 async16 each) ----
#pragma unroll
    for (int b = 0; b < 2; ++b) {
        short* dst = (short*)lds + b * BUFSZ;
        async16(gA0,      dst + dA0);       async16(gA0 + 32, dst + dA0 + 512);
        async16(gA1,      dst + dA1);       async16(gA1 + 32, dst + dA1 + 512);
        async16(gB0,      dst + dB0);       async16(gB0 + 32, dst + dB0 + 512);
        async16(gB1,      dst + dB1);       async16(gB1 + 32, dst + dB1 + 512);
        gA0 += BK2; gA1 += BK2; gB0 += BK2; gB1 += BK2;
    }
    asm volatile("s_waitcnt vmcnt(8)" ::: "memory");   // tile 0 landed
    SBAR();

    for (int t = 0; t < KT2; ++t) {
        const short* rb = lds + (t & 1) * BUFSZ;
        short* sb = (short*)rb;                        // stage target (tile t+2)
        const bool st = (t < KT2 - 2);

        // ---- phase 0: read A(m0-3) + B(n0-1); MFMA q(m0-3 x n0-1) ----
#pragma unroll
        for (int mi = 0; mi < 4; ++mi)
#pragma unroll
            for (int kh = 0; kh < 2; ++kh)
                af[mi][kh] = *(const bfrag8*)(rb + ((wm * 8 + mi) * 2 + kh) * 512 + lo8);
#pragma unroll
        for (int ni = 0; ni < 2; ++ni)
#pragma unroll
            for (int kh = 0; kh < 2; ++kh)
                bf[ni][kh] = *(const bfrag8*)(rb + ABUF + ((wn * 4 + ni) * 2 + kh) * 512 + lo8);
        SBAR();
        LGKM0();
        __builtin_amdgcn_s_setprio(1);
#pragma unroll
        for (int mi = 0; mi < 4; ++mi)
#pragma unroll
            for (int ni = 0; ni < 2; ++ni)
#pragma unroll
                for (int kh = 0; kh < 2; ++kh)
                    acc[mi][ni] = __builtin_amdgcn_mfma_f32_16x16x32_bf16(
                        af[mi][kh], bf[ni][kh], acc[mi][ni], 0, 0, 0);
        __builtin_amdgcn_s_setprio(0);
        SBAR();

        // ---- phase 1: read B(n2-3); MFMA q(m0-3 x n2-3) ----
#pragma unroll
        for (int ni = 2; ni < 4; ++ni)
#pragma unroll
            for (int kh = 0; kh < 2; ++kh)
                bf[ni][kh] = *(const bfrag8*)(rb + ABUF + ((wn * 4 + ni) * 2 + kh) * 512 + lo8);
        SBAR();
        LGKM0();
        __builtin_amdgcn_s_setprio(1);
#pragma unroll
        for (int mi = 0; mi < 4; ++mi)
#pragma unroll
            for (int ni = 2; ni < 4; ++ni)
#pragma unroll
                for (int kh = 0; kh < 2; ++kh)
                    acc[mi][ni] = __builtin_amdgcn_mfma_f32_16x16x32_bf16(
                        af[mi][kh], bf[ni][kh], acc[mi][ni], 0, 0, 0);
        __builtin_amdgcn_s_setprio(0);
        SBAR();

        // ---- phase 2: read A(m4-7); stage B(t+2); MFMA q(m4-7 x n0-1) ----
#pragma unroll
        for (int mi = 0; mi < 4; ++mi)
#pragma unroll
            for (int kh = 0; kh < 2; ++kh)
                af[mi][kh] = *(const bfrag8*)(rb + ((wm * 8 + 4 + mi) * 2 + kh) * 512 + lo8);
        if (st) {
            async16(gB0,      sb + dB0);    async16(gB0 + 32, sb + dB0 + 512);
            async16(gB1,      sb + dB1);    async16(gB1 + 32, sb + dB1 + 512);
        }
        SBAR();
        LGKM0();
        __builtin_amdgcn_s_setprio(1);
#pragma unroll
        for (int mi = 0; mi < 4; ++mi)
#pragma unroll
            for (int ni = 0; ni < 2; ++ni)
#pragma unroll
                for (int kh = 0; kh < 2; ++kh)
                    acc[4 + mi][ni] = __builtin_amdgcn_mfma_f32_16x16x32_bf16(
                        af[mi][kh], bf[ni][kh], acc[4 + mi][ni], 0, 0, 0);
        __builtin_amdgcn_s_setprio(0);
        SBAR();

        // ---- phase 3: stage A(t+2); MFMA q(m4-7 x n2-3); boundary vmcnt ----
        if (st) {
            async16(gA0,      sb + dA0);    async16(gA0 + 32, sb + dA0 + 512);
            async16(gA1,      sb + dA1);    async16(gA1 + 32, sb + dA1 + 512);
            gA0 += BK2; gA1 += BK2; gB0 += BK2; gB1 += BK2;
        }
        SBAR();
        __builtin_amdgcn_s_setprio(1);
#pragma unroll
        for (int mi = 0; mi < 4; ++mi)
#pragma unroll
            for (int ni = 2; ni < 4; ++ni)
#pragma unroll
                for (int kh = 0; kh < 2; ++kh)
                    acc[4 + mi][ni] = __builtin_amdgcn_mfma_f32_16x16x32_bf16(
                        af[mi][kh], bf[ni][kh], acc[4 + mi][ni], 0, 0, 0);
        __builtin_amdgcn_s_setprio(0);
        __builtin_amdgcn_sched_barrier(0);
        if (st) {
            asm volatile("s_waitcnt vmcnt(8)" ::: "memory");   // tile t+1 landed
        } else if (t == KT2 - 2) {
            asm volatile("s_waitcnt vmcnt(0)" ::: "memory");   // last tile landed
        }
        if (t < KT2 - 1) SBAR();
    }

    // ---- epilogue: out[m] += sum_n gelu(h + b1[n]) * W2[n] ----
    const int nbase = c * 1024 + nb2 * 256 + wn * 64 + l16;
    float b1v[4], w2v[4];
#pragma unroll
    for (int ni = 0; ni < 4; ++ni) {
        b1v[ni] = b1[nbase + ni * 16];
        w2v[ni] = W2[nbase + ni * 16];
    }

    float* outp = out + (size_t)(mb * 2 + wm) * 8192 + c * 128 + quad * 4;
#pragma unroll
    for (int mi = 0; mi < 8; ++mi) {
        float s[4] = {0.f, 0.f, 0.f, 0.f};
#pragma unroll
        for (int ni = 0; ni < 4; ++ni) {
#pragma unroll
            for (int r = 0; r < 4; ++r) {
                float h = acc[mi][ni][r] + b1v[ni];
                s[r] += gelu_fast(h) * w2v[ni];
            }
        }
#pragma unroll
        for (int r = 0; r < 4; ++r) {
            s[r] += __shfl_xor(s[r], 8, 64);
            s[r] += __shfl_xor(s[r], 4, 64);
            s[r] += __shfl_xor(s[r], 2, 64);
            s[r] += __shfl_xor(s[r], 1, 64);
            if (l16 == 0) atomicAdd(outp + mi * 16 + r, s[r]);
        }
    }
}

// ---------------- fallback (round-0 kernel, used if ws too small) ----------------
__global__ __launch_bounds__(256) void mlp_head_fallback(
    const float* __restrict__ x,  const float* __restrict__ W1,
    const float* __restrict__ b1, const float* __restrict__ W2,
    float* __restrict__ out)
{
    const int bid = blockIdx.x;
    const int nb = bid & 7;
    const int mb = (bid >> 3) & 15;
    const int c  = bid >> 7;

    __shared__ __align__(16) short lds_a[BM * BK];
    __shared__ __align__(16) short lds_b[BN * BK];

    const int tid  = threadIdx.x;
    const int lane = tid & 63;
    const int wave = tid >> 6;
    const int wm = wave >> 1, wn = wave & 1;
    const int quad = lane >> 4, l16 = lane & 15;

    const int arow = tid & 127;
    const int akh  = tid >> 7;
    const float* aptr = x + ((size_t)mb * 8192 + (size_t)c * 128 + arow) * 1024 + akh * 16;
    short* aw0 = lds_a + (arow >> 4) * 512 + (akh * 2) * 128 + (arow & 15) * 8;
    short* aw1 = aw0 + 128;

    const int ncol = tid & 127;
    const int bkh  = tid >> 7;
    const float* bptr = W1 + (size_t)c * 1024 * 1024 + (size_t)(bkh * 16) * 1024
                           + (size_t)nb * 128 + ncol;
    short* bw0 = lds_b + (ncol >> 4) * 512 + (bkh * 2) * 128 + (ncol & 15) * 8;
    short* bw1 = bw0 + 128;

    const short* ard = lds_a + (wm * 4) * 512 + quad * 128 + l16 * 8;
    const short* brd = lds_b + (wn * 4) * 512 + quad * 128 + l16 * 8;

    ffrag4 acc[4][4] = {};

    for (int kt = 0; kt < EMB / BK; ++kt) {
        float4 a0 = *(const float4*)(aptr + 0);
        float4 a1 = *(const float4*)(aptr + 4);
        float4 a2 = *(const float4*)(aptr + 8);
        float4 a3 = *(const float4*)(aptr + 12);
        float bv[16];
#pragma unroll
        for (int j = 0; j < 16; ++j) bv[j] = bptr[(size_t)j * 1024];
        aptr += BK;
        bptr += (size_t)BK * 1024;

        __syncthreads();

        S8 pa0, pa1, pb0, pb1;
        pa0.u[0] = pk2(a0.x, a0.y); pa0.u[1] = pk2(a0.z, a0.w);
        pa0.u[2] = pk2(a1.x, a1.y); pa0.u[3] = pk2(a1.z, a1.w);
        pa1.u[0] = pk2(a2.x, a2.y); pa1.u[1] = pk2(a2.z, a2.w);
        pa1.u[2] = pk2(a3.x, a3.y); pa1.u[3] = pk2(a3.z, a3.w);
#pragma unroll
        for (int j = 0; j < 4; ++j) pb0.u[j] = pk2(bv[2 * j], bv[2 * j + 1]);
#pragma unroll
        for (int j = 0; j < 4; ++j) pb1.u[j] = pk2(bv[8 + 2 * j], bv[9 + 2 * j]);

        *(bfrag8*)aw0 = pa0.s;
        *(bfrag8*)aw1 = pa1.s;
        *(bfrag8*)bw0 = pb0.s;
        *(bfrag8*)bw1 = pb1.s;

        __syncthreads();

        bfrag8 af[4], bf[4];
#pragma unroll
        for (int mi = 0; mi < 4; ++mi) af[mi] = *(const bfrag8*)(ard + mi * 512);
#pragma unroll
        for (int ni = 0; ni < 4; ++ni) bf[ni] = *(const bfrag8*)(brd + ni * 512);
#pragma unroll
        for (int mi = 0; mi < 4; ++mi)
#pragma unroll
            for (int ni = 0; ni < 4; ++ni)
                acc[mi][ni] = __builtin_amdgcn_mfma_f32_16x16x32_bf16(
                    af[mi], bf[ni], acc[mi][ni], 0, 0, 0);
    }

    const int nbase = c * 1024 + nb * 128 + wn * 64 + l16;
    float b1v[4], w2v[4];
#pragma unroll
    for (int ni = 0; ni < 4; ++ni) {
        b1v[ni] = b1[nbase + ni * 16];
        w2v[ni] = W2[nbase + ni * 16];
    }

    float* outp = out + (size_t)mb * 8192 + c * 128 + wm * 64 + quad * 4;
#pragma unroll
    for (int mi = 0; mi < 4; ++mi) {
        float s[4] = {0.f, 0.f, 0.f, 0.f};
#pragma unroll
        for (int ni = 0; ni < 4; ++ni) {
#pragma unroll
            for (int r = 0; r < 4; ++r) {
                float h = acc[mi][ni][r] + b1v[ni];
                s[r] += gelu_fast(h) * w2v[ni];
            }
        }
#pragma unroll
        for (int r = 0; r < 4; ++r) {
            s[r] += __shfl_xor(s[r], 8, 64);
            s[r] += __shfl_xor(s[r], 4, 64);
            s[r] += __shfl_xor(s[r], 2, 64);
            s[r] += __shfl_xor(s[r], 1, 64);
            if (l16 == 0) atomicAdd(outp + mi * 16 + r, s[r]);
        }
    }
}

extern "C" void kernel_launch(void* const* d_in, const int* in_sizes, int n_in,
                              void* d_out, int out_size, void* d_ws, size_t ws_size,
                              hipStream_t stream) {
    const float* x  = (const float*)d_in[0];
    const float* W1 = (const float*)d_in[1];
    const float* b1 = (const float*)d_in[2];
    const float* W2 = (const float*)d_in[3];
    const float* b2 = (const float*)d_in[4];
    float* out = (float*)d_out;

    const size_t xb_bytes  = (size_t)NBATCH * NCLS * TDIM * EMB * 2;      // 268435456
    const size_t w1t_bytes = (size_t)NCLS * EMB * EMB * 2;                // 134217728

    init_out<<<dim3(512), dim3(256), 0, stream>>>(b2, out);

    if (ws_size >= xb_bytes + w1t_bytes) {
        short* xb  = (short*)d_ws;
        short* w1t = (short*)((char*)d_ws + xb_bytes);
        cvt_x<<<dim3(16384), dim3(256), 0, stream>>>(x, xb);
        cvt_w1t<<<dim3(16384), dim3(256), 0, stream>>>(W1, w1t);
        mlp_gemm8<<<dim3(2048), dim3(512), 0, stream>>>(xb, w1t, b1, W2, out);
    } else {
        mlp_head_fallback<<<dim3(NCLS * 16 * 8), dim3(256), 0, stream>>>(x, W1, b1, W2, out);
    }
}